// Round 1
// baseline (349.685 us; speedup 1.0000x reference)
//
#include <hip/hip_runtime.h>
#include <math.h>

#define EPSV 1e-5f

__device__ __forceinline__ float fast_rcp(float x) {
#if __has_builtin(__builtin_amdgcn_rcpf)
    return __builtin_amdgcn_rcpf(x);
#else
    return 1.0f / x;
#endif
}

__device__ __forceinline__ float sigmoidf_(float x) {
    return fast_rcp(1.0f + __expf(-x));
}

// ---------------------------------------------------------------------------
// Kernel A: per (bg,c) plane: row means (over w), col means (over h),
// plane mean, plane var.  grid = 8192 (bg*64+c), block = 256.
// Each thread: 4 float4 loads, f = t + 256k -> row = (t>>4) + 16k, colquad = t&15
// ---------------------------------------------------------------------------
__global__ __launch_bounds__(256) void k_stats1(
    const float* __restrict__ x,
    float* __restrict__ rowmean,   // [8192][64]
    float* __restrict__ colmean,   // [8192][64]
    float* __restrict__ meanA,     // [8192]
    float* __restrict__ varA)      // [8192]
{
    int blk = blockIdx.x;
    const float4* p4 = (const float4*)(x + (size_t)blk * 4096);
    int t = threadIdx.x;
    int g = t >> 4, cl = t & 15;
    float cp0 = 0.f, cp1 = 0.f, cp2 = 0.f, cp3 = 0.f, s = 0.f, ss = 0.f;
    __shared__ float colacc[16][64];
    __shared__ float red[8];
#pragma unroll
    for (int k = 0; k < 4; ++k) {
        float4 v = p4[t + 256 * k];
        float rp = v.x + v.y + v.z + v.w;
        s += rp;
        ss += v.x * v.x + v.y * v.y + v.z * v.z + v.w * v.w;
        cp0 += v.x; cp1 += v.y; cp2 += v.z; cp3 += v.w;
        // row sum: reduce across the 16 lanes holding this row
#pragma unroll
        for (int m = 8; m >= 1; m >>= 1) rp += __shfl_xor(rp, m, 16);
        if (cl == 0) rowmean[(size_t)blk * 64 + g + 16 * k] = rp * (1.0f / 64.0f);
    }
    colacc[g][cl * 4 + 0] = cp0;
    colacc[g][cl * 4 + 1] = cp1;
    colacc[g][cl * 4 + 2] = cp2;
    colacc[g][cl * 4 + 3] = cp3;
    // block reduce s, ss
#pragma unroll
    for (int m = 32; m >= 1; m >>= 1) { s += __shfl_xor(s, m); ss += __shfl_xor(ss, m); }
    int wv = t >> 6;
    if ((t & 63) == 0) { red[wv] = s; red[4 + wv] = ss; }
    __syncthreads();
    if (t < 64) {
        float cs = 0.f;
#pragma unroll
        for (int gg = 0; gg < 16; ++gg) cs += colacc[gg][t];
        colmean[(size_t)blk * 64 + t] = cs * (1.0f / 64.0f);
    }
    if (t == 0) {
        float S = red[0] + red[1] + red[2] + red[3];
        float SS = red[4] + red[5] + red[6] + red[7];
        float m = S * (1.0f / 4096.0f);
        meanA[blk] = m;
        varA[blk] = SS * (1.0f / 4096.0f) - m * m;
    }
}

// ---------------------------------------------------------------------------
// Kernel B: 64x64 conv1x1 over row/col means + sigmoid.
// grid = 256 (bg*2 + rc), block = 256. lane = h; registers hold rm column.
// ---------------------------------------------------------------------------
__global__ __launch_bounds__(256) void k_conv(
    const float* __restrict__ W, const float* __restrict__ Wb,
    const float* __restrict__ rowmean, const float* __restrict__ colmean,
    float* __restrict__ shg, float* __restrict__ swg)
{
    int blk = blockIdx.x;
    int bg = blk >> 1, rc = blk & 1;
    const float* rm = (rc ? colmean : rowmean) + (size_t)bg * 4096;
    float* outp = (rc ? swg : shg) + (size_t)bg * 4096;
    int t = threadIdx.x, lane = t & 63, wv = t >> 6;
    float r[64];
#pragma unroll
    for (int i = 0; i < 64; ++i) r[i] = rm[i * 64 + lane];
    for (int j = 0; j < 16; ++j) {
        int c = wv * 16 + j;
        float acc = Wb[c];
#pragma unroll
        for (int i = 0; i < 64; ++i)
            acc = fmaf(W[c * 64 + i], r[i], acc);
        outp[c * 64 + lane] = sigmoidf_(acc);  // coalesced store
    }
}

// ---------------------------------------------------------------------------
// Kernel C: second stats pass: mean/var of t = x*sh*sw; spatial channel means.
// grid = 8192, block = 256.
// ---------------------------------------------------------------------------
__global__ __launch_bounds__(256) void k_stats2(
    const float* __restrict__ x,
    const float* __restrict__ shg, const float* __restrict__ swg,
    const float* __restrict__ meanA, const float* __restrict__ varA,
    const float* __restrict__ swt, const float* __restrict__ sbs,
    const float* __restrict__ gn1w, const float* __restrict__ gn1b,
    float* __restrict__ meanT, float* __restrict__ varT,
    float* __restrict__ spat)   // [128][32]
{
    int blk = blockIdx.x;
    int c = blk & 63, bg = blk >> 6;
    const float4* p4 = (const float4*)(x + (size_t)blk * 4096);
    int t = threadIdx.x;
    int g = t >> 4, cl = t & 15;
    float4 sw4 = ((const float4*)(swg + (size_t)blk * 64))[cl];
    float a = 0.f, bb = 0.f;
    bool spatial = (c >= 32);
    if (spatial) {
        int i = c - 32;
        float mu = meanA[blk];
        float r2 = rsqrtf(varA[blk] + EPSV);
        a = swt[i] * gn1w[i] * r2;
        bb = swt[i] * (gn1b[i] - mu * r2 * gn1w[i]) + sbs[i];
    }
    float st = 0.f, sst = 0.f, ssp = 0.f;
#pragma unroll
    for (int k = 0; k < 4; ++k) {
        float4 v = p4[t + 256 * k];
        float sh = shg[(size_t)blk * 64 + g + 16 * k];
        float t0 = v.x * sh * sw4.x;
        float t1 = v.y * sh * sw4.y;
        float t2 = v.z * sh * sw4.z;
        float t3 = v.w * sh * sw4.w;
        st += t0 + t1 + t2 + t3;
        sst += t0 * t0 + t1 * t1 + t2 * t2 + t3 * t3;
        if (spatial) {
            ssp += v.x * sigmoidf_(fmaf(a, v.x, bb))
                 + v.y * sigmoidf_(fmaf(a, v.y, bb))
                 + v.z * sigmoidf_(fmaf(a, v.z, bb))
                 + v.w * sigmoidf_(fmaf(a, v.w, bb));
        }
    }
#pragma unroll
    for (int m = 32; m >= 1; m >>= 1) {
        st += __shfl_xor(st, m); sst += __shfl_xor(sst, m); ssp += __shfl_xor(ssp, m);
    }
    __shared__ float red[12];
    int wv = t >> 6;
    if ((t & 63) == 0) { red[wv] = st; red[4 + wv] = sst; red[8 + wv] = ssp; }
    __syncthreads();
    if (t == 0) {
        float S = red[0] + red[1] + red[2] + red[3];
        float SS = red[4] + red[5] + red[6] + red[7];
        float m = S * (1.0f / 4096.0f);
        meanT[blk] = m;
        varT[blk] = SS * (1.0f / 4096.0f) - m * m;
        if (spatial) {
            float SP = red[8] + red[9] + red[10] + red[11];
            spat[bg * 32 + (c - 32)] = SP * (1.0f / 4096.0f);
        }
    }
}

// ---------------------------------------------------------------------------
// Kernel D: per-bg softmaxes + coefficient folding. grid = 128, block = 64.
// ---------------------------------------------------------------------------
__global__ __launch_bounds__(64) void k_coef(
    const float* __restrict__ meanA, const float* __restrict__ varA,
    const float* __restrict__ meanT, const float* __restrict__ varT,
    const float* __restrict__ spat,
    const float* __restrict__ gnw, const float* __restrict__ gnb,
    const float* __restrict__ gn1w, const float* __restrict__ gn1b,
    const float* __restrict__ cwt, const float* __restrict__ cbs,
    const float* __restrict__ swt, const float* __restrict__ sbs,
    float* __restrict__ eArr,   // [128][64]
    float* __restrict__ gArr,   // [128][32]
    float* __restrict__ dArr,   // [128][32]
    float* __restrict__ aArr,   // [128][32]
    float* __restrict__ bArr,   // [128][32]
    float* __restrict__ kArr)   // [128]
{
    int bg = blockIdx.x;
    int c = threadIdx.x;                 // 0..63, one wave
    size_t idx = (size_t)bg * 64 + c;
    __shared__ float x2m[64], x11L[64], sL[32];
    if (c < 32) {
        float xc = meanA[idx];
        float s = sigmoidf_(fmaf(cwt[c], xc, cbs[c]));
        sL[c] = s;
        x2m[2 * c] = s * xc;             // mean of x_channel[c]
        x2m[2 * c + 1] = spat[bg * 32 + c];
    }
    __syncthreads();
    // x11 = softmax(gn_b)  (mean of normalized x1 == gn_b analytically)
    float v1 = gnb[c];
    float mx = v1;
#pragma unroll
    for (int m = 32; m >= 1; m >>= 1) mx = fmaxf(mx, __shfl_xor(mx, m));
    float e1 = __expf(v1 - mx);
    float s1 = e1;
#pragma unroll
    for (int m = 32; m >= 1; m >>= 1) s1 += __shfl_xor(s1, m);
    float x11 = e1 / s1;
    x11L[c] = x11;
    // x21 = softmax(x2 channel means)
    float v2 = x2m[c];
    mx = v2;
#pragma unroll
    for (int m = 32; m >= 1; m >>= 1) mx = fmaxf(mx, __shfl_xor(mx, m));
    float e2 = __expf(v2 - mx);
    float s2 = e2;
#pragma unroll
    for (int m = 32; m >= 1; m >>= 1) s2 += __shfl_xor(s2, m);
    float x21 = e2 / s2;

    float mt = meanT[idx];
    float rt = rsqrtf(varT[idx] + EPSV);
    eArr[idx] = x21 * gnw[c] * rt;
    float kp = x21 * (gnb[c] - gnw[c] * rt * mt);
#pragma unroll
    for (int m = 32; m >= 1; m >>= 1) kp += __shfl_xor(kp, m);
    if (c == 0) kArr[bg] = kp;
    __syncthreads();
    if (c < 32) {
        gArr[bg * 32 + c] = x11L[2 * c] * sL[c];
        dArr[bg * 32 + c] = x11L[2 * c + 1];
        size_t idx2 = (size_t)bg * 64 + 32 + c;
        float mu = meanA[idx2];
        float r2 = rsqrtf(varA[idx2] + EPSV);
        aArr[bg * 32 + c] = swt[c] * gn1w[c] * r2;
        bArr[bg * 32 + c] = swt[c] * (gn1b[c] - mu * r2 * gn1w[c]) + sbs[c];
    }
}

// ---------------------------------------------------------------------------
// Kernel E: final pass. grid = 512 (bg*4 + htile), block = 256,
// thread = one float4 (4 pixels in a row). Loop channels to build weights,
// sigmoid, then second loop to write out = x * sig(weights).
// ---------------------------------------------------------------------------
__global__ __launch_bounds__(256) void k_final(
    const float* __restrict__ x,
    const float* __restrict__ shg, const float* __restrict__ swg,
    const float* __restrict__ eArr, const float* __restrict__ gArr,
    const float* __restrict__ dArr, const float* __restrict__ aArr,
    const float* __restrict__ bArr, const float* __restrict__ kArr,
    float* __restrict__ outp)
{
    int blk = blockIdx.x;
    int bg = blk >> 2, tile = blk & 3;
    int h0 = tile << 4;
    int t = threadIdx.x;
    __shared__ float shL[64][16];
    __shared__ float4 swL[64][16];
    __shared__ float eL[64], gL[32], dL[32], aL[32], bL[32];
    for (int idx = t; idx < 1024; idx += 256) {
        int c = idx >> 4, q = idx & 15;
        shL[c][q] = shg[((size_t)bg * 64 + c) * 64 + h0 + q];
        swL[c][q] = ((const float4*)swg)[((size_t)bg * 64 + c) * 16 + q];
    }
    if (t < 64)       eL[t]        = eArr[(size_t)bg * 64 + t];
    else if (t < 96)  gL[t - 64]   = gArr[bg * 32 + t - 64];
    else if (t < 128) dL[t - 96]   = dArr[bg * 32 + t - 96];
    else if (t < 160) aL[t - 128]  = aArr[bg * 32 + t - 128];
    else if (t < 192) bL[t - 160]  = bArr[bg * 32 + t - 160];
    __syncthreads();
    int hl = t >> 4, w4 = t & 15;
    const float* xp = x + (size_t)bg * 64 * 4096 + (size_t)(h0 + hl) * 64 + w4 * 4;
    float K = kArr[bg];
    float ax = K, ay = K, az = K, aw = K;
#pragma unroll 8
    for (int c = 0; c < 32; ++c) {
        float4 v = *(const float4*)(xp + (size_t)c * 4096);
        float4 s4 = swL[c][w4];
        float ce = eL[c] * shL[c][hl];
        float gc = gL[c];
        ax = fmaf(fmaf(ce, s4.x, gc), v.x, ax);
        ay = fmaf(fmaf(ce, s4.y, gc), v.y, ay);
        az = fmaf(fmaf(ce, s4.z, gc), v.z, az);
        aw = fmaf(fmaf(ce, s4.w, gc), v.w, aw);
    }
#pragma unroll 8
    for (int i = 0; i < 32; ++i) {
        int c = 32 + i;
        float4 v = *(const float4*)(xp + (size_t)c * 4096);
        float4 s4 = swL[c][w4];
        float ce = eL[c] * shL[c][hl];
        float ai = aL[i], bi = bL[i], di = dL[i];
        ax = fmaf(ce * s4.x, v.x, ax); ax = fmaf(di * v.x, sigmoidf_(fmaf(ai, v.x, bi)), ax);
        ay = fmaf(ce * s4.y, v.y, ay); ay = fmaf(di * v.y, sigmoidf_(fmaf(ai, v.y, bi)), ay);
        az = fmaf(ce * s4.z, v.z, az); az = fmaf(di * v.z, sigmoidf_(fmaf(ai, v.z, bi)), az);
        aw = fmaf(ce * s4.w, v.w, aw); aw = fmaf(di * v.w, sigmoidf_(fmaf(ai, v.w, bi)), aw);
    }
    float sx = sigmoidf_(ax), sy = sigmoidf_(ay), sz = sigmoidf_(az), sw_ = sigmoidf_(aw);
    float* op = outp + (xp - x);
#pragma unroll 8
    for (int c = 0; c < 64; ++c) {
        float4 v = *(const float4*)(xp + (size_t)c * 4096);
        float4 o = { v.x * sx, v.y * sy, v.z * sz, v.w * sw_ };
        *(float4*)(op + (size_t)c * 4096) = o;
    }
}

// ---------------------------------------------------------------------------
extern "C" void kernel_launch(void* const* d_in, const int* in_sizes, int n_in,
                              void* d_out, int out_size, void* d_ws, size_t ws_size,
                              hipStream_t stream) {
    (void)in_sizes; (void)n_in; (void)out_size; (void)ws_size;
    const float* x    = (const float*)d_in[0];
    const float* W    = (const float*)d_in[1];
    const float* Wb   = (const float*)d_in[2];
    const float* gnw  = (const float*)d_in[3];
    const float* gnb  = (const float*)d_in[4];
    const float* gn1w = (const float*)d_in[5];
    const float* gn1b = (const float*)d_in[6];
    const float* cwt  = (const float*)d_in[7];
    const float* cbs  = (const float*)d_in[8];
    const float* swt  = (const float*)d_in[9];
    const float* sbs  = (const float*)d_in[10];
    float* out = (float*)d_out;
    float* ws = (float*)d_ws;

    float* rowmean = ws;                    // 524288
    float* colmean = rowmean + 524288;      // 524288
    float* shg     = colmean + 524288;      // 524288
    float* swg     = shg + 524288;          // 524288
    float* meanA   = swg + 524288;          // 8192
    float* varA    = meanA + 8192;          // 8192
    float* meanT   = varA + 8192;           // 8192
    float* varT    = meanT + 8192;          // 8192
    float* spat    = varT + 8192;           // 4096
    float* eArr    = spat + 4096;           // 8192
    float* gArr    = eArr + 8192;           // 4096
    float* dArr    = gArr + 4096;           // 4096
    float* aArr    = dArr + 4096;           // 4096
    float* bArr    = aArr + 4096;           // 4096
    float* kArr    = bArr + 4096;           // 128

    k_stats1<<<8192, 256, 0, stream>>>(x, rowmean, colmean, meanA, varA);
    k_conv<<<256, 256, 0, stream>>>(W, Wb, rowmean, colmean, shg, swg);
    k_stats2<<<8192, 256, 0, stream>>>(x, shg, swg, meanA, varA, swt, sbs, gn1w, gn1b,
                                       meanT, varT, spat);
    k_coef<<<128, 64, 0, stream>>>(meanA, varA, meanT, varT, spat, gnw, gnb, gn1w, gn1b,
                                   cwt, cbs, swt, sbs, eArr, gArr, dArr, aArr, bArr, kArr);
    k_final<<<512, 256, 0, stream>>>(x, shg, swg, eArr, gArr, dArr, aArr, bArr, kArr, out);
}